// Round 12
// baseline (248.129 us; speedup 1.0000x reference)
//
#include <hip/hip_runtime.h>
#include <math.h>

#define NN   1024
#define FF   32
#define HID  64
#define OUTF 32
#define ITER 8

typedef unsigned int  uint;
typedef unsigned short ushort;
typedef _Float16 halfx8  __attribute__((ext_vector_type(8)));
typedef __fp16   fp16x2  __attribute__((ext_vector_type(2)));
typedef float    floatx16 __attribute__((ext_vector_type(16)));

// ws layout (float offsets)
#define WS_A    0                      // N*HID : A rows (plain)
#define WS_B    (WS_A + NN*HID)        // 65536 : B in FRAGMENT order (see prep)
#define WS_C4   (WS_B + NN*HID)        // 131072  (N x 4: x,y,z,0)
#define WS_B1   (WS_C4 + NN*4)         // 135168
#define WS_B2   (WS_B1 + HID)          // 135232 (pad to 64)
#define WS_W2H  (WS_B2 + 64)           // 135296  ushort[4*64*8] = 1024 floats

// B fragment order: per 32-j tile: [lo/hi half16][c 0..3][lane 0..63] float4.
// tile = j>>5, lane = (h>>3 & 1)*32 + (j&31), c = h>>4, within-f4 = h&3,
// half16 = (h>>2) & 1.   512 float4 per tile; block bx needs tiles 4bx..4bx+3
// = 2048 contiguous float4 -> linear coalesced LDS copy, conflict-free
// ds_read_b128 (lane stride 16 B).

__device__ __forceinline__ float swish(float x) {
    // x * sigmoid(x); v_exp_f32 / v_rcp_f32, abs err ~1e-5 max — far under budget
    float e = __builtin_amdgcn_exp2f(x * -1.442695040888963f);
    return x * __builtin_amdgcn_rcpf(1.0f + e);
}

__global__ void prep_kernel(
    const float* __restrict__ Coords,
    const float* __restrict__ Emb,
    const float* __restrict__ W1,
    const float* __restrict__ b1,
    const float* __restrict__ W2,
    const float* __restrict__ b2,
    float* __restrict__ ws)
{
    const int b = blockIdx.x;
    const int t = threadIdx.x;
    if (b < NN) {
        // A[b][t] = Emb[b] . W1[t][0:F];  B[b][t] = Emb[b] . W1[t][F:2F]
        const float4* w1v = (const float4*)(W1 + t * (2 * FF));
        const float4* ev  = (const float4*)(Emb + b * FF);
        float accA = 0.f, accB = 0.f;
        #pragma unroll
        for (int f4 = 0; f4 < FF / 4; ++f4) {
            const float4 e  = ev[f4];
            const float4 a  = w1v[f4];
            const float4 bq = w1v[FF / 4 + f4];
            accA = fmaf(e.x, a.x,  fmaf(e.y, a.y,  fmaf(e.z, a.z,  fmaf(e.w, a.w,  accA))));
            accB = fmaf(e.x, bq.x, fmaf(e.y, bq.y, fmaf(e.z, bq.z, fmaf(e.w, bq.w, accB))));
        }
        ws[WS_A + b * HID + t] = accA;
        // scatter accB into fragment order (j = b, h = t)
        const int tile = b >> 5;
        const int c    = t >> 4;
        const int hf   = (t >> 3) & 1;
        const int k    = t & 7;
        const int h16  = k >> 2;
        const int lane = hf * 32 + (b & 31);
        const int f4i  = tile * 512 + h16 * 256 + c * 64 + lane;
        ws[WS_B + f4i * 4 + (k & 3)] = accB;
    } else {
        if (t < HID)  ws[WS_B1 + t] = b1[t];
        if (t < OUTF) ws[WS_B2 + t] = b2[t];
        #pragma unroll 1
        for (int n = t; n < NN; n += 64) {
            ws[WS_C4 + n * 4 + 0] = Coords[n * 3 + 0];
            ws[WS_C4 + n * 4 + 1] = Coords[n * 3 + 1];
            ws[WS_C4 + n * 4 + 2] = Coords[n * 3 + 2];
            ws[WS_C4 + n * 4 + 3] = 0.f;
        }
        // W2^T fragments in MFMA B-layout (32x32x16): n = t&31, k = (t>>5)*8 + j
        ushort* w2h = (ushort*)(ws + WS_W2H);
        const int n  = t & 31;
        const int kh = (t >> 5) * 8;
        #pragma unroll
        for (int c = 0; c < 4; ++c) {
            #pragma unroll
            for (int j = 0; j < 8; ++j) {
                const int k = c * 16 + kh + j;
                union { _Float16 h; ushort u; } cv;
                cv.h = (_Float16)W2[n * HID + k];
                w2h[(c * 64 + t) * 8 + j] = cv.u;
            }
        }
    }
}

// R2 structure + DUAL-I ILP, with bv moved VGPR->LDS to avoid R10's spill.
// R10/R11 counters: traffic is ideal (FETCH 5 MB, WRITE 135 MB) but the loop
// is latency-bound (~80 us vs ~25 us issue floor, VALUBusy ~25-31%). Dual-i
// gives two independent swish/pack/MFMA chains; LDS-resident bv keeps peak
// VGPR ~105 < 128 cap so 4 blocks/CU residency holds with no scratch.
// LDS: A 2KB | b1 | ci | bv 32KB = ~35 KB -> 4 blocks/CU (140/160 KB).
__global__ __launch_bounds__(256, 4) void main_kernel(
    const float* __restrict__ Edges,
    const float* __restrict__ ws,
    float* __restrict__ out)
{
    __shared__ float lds[ITER * HID + HID + ITER * 4 + 8192];
    #define L_A   0
    #define L_B1  (ITER * HID)
    #define L_CI  (ITER * HID + HID)
    #define L_BV  (ITER * HID + HID + ITER * 4)   // 608, f4-aligned

    const int t    = threadIdx.x;
    const int lane = t & 63;
    const int wave = t >> 6;
    const int j0   = blockIdx.x * 128 + wave * 32;
    const int i0   = blockIdx.y * ITER;
    const int p    = lane & 31;
    const int half = lane >> 5;
    const int jp   = j0 + p;

    // ---- stage LDS ----
    {
        const float* srcA = ws + WS_A + (size_t)i0 * HID;   // 512 contiguous floats
        if (t < 128) {
            *(float4*)&lds[L_A + t * 4] = *(const float4*)(srcA + t * 4);
        } else if (t < 144) {
            *(float4*)&lds[L_B1 + (t - 128) * 4] =
                *(const float4*)(ws + WS_B1 + (t - 128) * 4);
        } else if (t < 152) {
            *(float4*)&lds[L_CI + (t - 144) * 4] =
                *(const float4*)(ws + WS_C4 + (size_t)(i0 + (t - 144)) * 4);
        }
        // bv: linear copy of 2048 float4 (block's 4 tiles, fragment order)
        const float4* srcB = (const float4*)(ws + WS_B) + (size_t)blockIdx.x * 2048;
        float4* dstB = (float4*)&lds[L_BV];
        #pragma unroll
        for (int k = 0; k < 8; ++k)
            dstB[t + 256 * k] = srcB[t + 256 * k];
    }

    // ---- loop-invariant state (VGPRs) ----
    const ushort* w2hp = (const ushort*)(ws + WS_W2H);
    halfx8 bh[4];
    #pragma unroll
    for (int c = 0; c < 4; ++c)
        bh[c] = *(const halfx8*)(w2hp + (c * 64 + lane) * 8);

    const float4 cj  = *(const float4*)(ws + WS_C4 + (size_t)jp * 4);
    const float  b2n = ws[WS_B2 + p];

    __syncthreads();

    // Edges software pipeline: two rows in flight
    const float* egp = Edges + (size_t)i0 * NN + jp;
    float eg0 = egp[0];
    float eg1 = egp[NN];

    #pragma unroll 1
    for (int it = 0; it < ITER; it += 2) {
        const float e0 = eg0, e1 = eg1;
        if (it + 2 < ITER) {                 // prefetch next pair
            eg0 = egp[(size_t)(it + 2) * NN];
            eg1 = egp[(size_t)(it + 3) * NN];
        }

        const float4 ci0 = *(const float4*)&lds[L_CI + it * 4];
        const float4 ci1 = *(const float4*)&lds[L_CI + (it + 1) * 4];
        const float dx0 = ci0.x - cj.x, dy0 = ci0.y - cj.y, dz0 = ci0.z - cj.z;
        const float dx1 = ci1.x - cj.x, dy1 = ci1.y - cj.y, dz1 = ci1.z - cj.z;
        const float w0 = e0 * sqrtf(dx0 * dx0 + dy0 * dy0 + dz0 * dz0);
        const float w1 = e1 * sqrtf(dx1 * dx1 + dy1 * dy1 + dz1 * dz1);

        floatx16 acc0, acc1;
        #pragma unroll
        for (int r = 0; r < 16; ++r) { acc0[r] = b2n; acc1[r] = b2n; }
        #pragma unroll
        for (int c = 0; c < 4; ++c) {
            const int ho = c * 16 + half * 8;
            float av0[8], av1[8], b1c[8], bvv[8];
            *(float4*)(av0 + 0) = *(const float4*)&lds[L_A + it * HID + ho];
            *(float4*)(av0 + 4) = *(const float4*)&lds[L_A + it * HID + ho + 4];
            *(float4*)(av1 + 0) = *(const float4*)&lds[L_A + (it + 1) * HID + ho];
            *(float4*)(av1 + 4) = *(const float4*)&lds[L_A + (it + 1) * HID + ho + 4];
            *(float4*)(b1c + 0) = *(const float4*)&lds[L_B1 + ho];
            *(float4*)(b1c + 4) = *(const float4*)&lds[L_B1 + ho + 4];
            // fragment-ordered bv: lo at [wave*512 + c*64 + lane], hi at +256 f4
            *(float4*)(bvv + 0) = *(const float4*)&lds[L_BV + (wave * 512 + c * 64 + lane) * 4];
            *(float4*)(bvv + 4) = *(const float4*)&lds[L_BV + (wave * 512 + 256 + c * 64 + lane) * 4];
            union FragH { fp16x2 h2[4]; halfx8 v; } ah0, ah1;
            #pragma unroll
            for (int jj = 0; jj < 8; jj += 2) {
                const float q0 = fmaf(w0, av0[jj]     + bvv[jj],     b1c[jj]);
                const float q1 = fmaf(w0, av0[jj + 1] + bvv[jj + 1], b1c[jj + 1]);
                const float r0 = fmaf(w1, av1[jj]     + bvv[jj],     b1c[jj]);
                const float r1 = fmaf(w1, av1[jj + 1] + bvv[jj + 1], b1c[jj + 1]);
                ah0.h2[jj >> 1] = __builtin_amdgcn_cvt_pkrtz(swish(q0), swish(q1));
                ah1.h2[jj >> 1] = __builtin_amdgcn_cvt_pkrtz(swish(r0), swish(r1));
            }
            acc0 = __builtin_amdgcn_mfma_f32_32x32x16_f16(ah0.v, bh[c], acc0, 0, 0, 0);
            acc1 = __builtin_amdgcn_mfma_f32_32x32x16_f16(ah1.v, bh[c], acc1, 0, 0, 0);
        }

        // epilogue: C/D layout n = p (output), m = (r&3) + 8*(r>>2) + 4*half (j)
        // each NT dword-store instruction covers two dense 128-B row segments
        float* __restrict__ ob0 = out + ((size_t)(i0 + it)     * NN + j0) * OUTF + p;
        #pragma unroll
        for (int r = 0; r < 16; ++r) {
            const int m = (r & 3) + 8 * (r >> 2) + 4 * half;
            __builtin_nontemporal_store(swish(acc0[r]), ob0 + m * OUTF);
        }
        float* __restrict__ ob1 = out + ((size_t)(i0 + it + 1) * NN + j0) * OUTF + p;
        #pragma unroll
        for (int r = 0; r < 16; ++r) {
            const int m = (r & 3) + 8 * (r >> 2) + 4 * half;
            __builtin_nontemporal_store(swish(acc1[r]), ob1 + m * OUTF);
        }
    }
}

extern "C" void kernel_launch(void* const* d_in, const int* in_sizes, int n_in,
                              void* d_out, int out_size, void* d_ws, size_t ws_size,
                              hipStream_t stream)
{
    const float* Edges  = (const float*)d_in[0];
    const float* Coords = (const float*)d_in[1];
    const float* Emb    = (const float*)d_in[2];
    const float* W1     = (const float*)d_in[3];
    const float* b1     = (const float*)d_in[4];
    const float* W2     = (const float*)d_in[5];
    const float* b2     = (const float*)d_in[6];
    float* ws  = (float*)d_ws;
    float* out = (float*)d_out;

    hipLaunchKernelGGL(prep_kernel, dim3(NN + 1), dim3(64), 0, stream,
                       Coords, Emb, W1, b1, W2, b2, ws);
    hipLaunchKernelGGL(main_kernel, dim3(NN / 128, NN / ITER), dim3(256), 0, stream,
                       Edges, ws, out);
}

// Round 14
// 169.978 us; speedup vs baseline: 1.4598x; 1.4598x over previous
//
#include <hip/hip_runtime.h>
#include <math.h>

#define NN   1024
#define FF   32
#define HID  64
#define OUTF 32
#define ITER 8

typedef unsigned int  uint;
typedef unsigned short ushort;
typedef _Float16 halfx8  __attribute__((ext_vector_type(8)));
typedef __fp16   fp16x2  __attribute__((ext_vector_type(2)));
typedef float    floatx16 __attribute__((ext_vector_type(16)));

// ws layout (float offsets)
#define WS_A    0                      // N*HID : A rows (plain)
#define WS_B    (WS_A + NN*HID)        // 65536 : B in FRAGMENT order (see prep)
#define WS_C4   (WS_B + NN*HID)        // 131072  (N x 4: x,y,z,0)
#define WS_B1   (WS_C4 + NN*4)         // 135168
#define WS_B2   (WS_B1 + HID)          // 135232 (pad to 64)
#define WS_W2H  (WS_B2 + 64)           // 135296  ushort[4*64*8] = 1024 floats

// B fragment order: per 32-j tile: [lo/hi half16][c 0..3][lane 0..63] float4.
// tile = j>>5, lane = (h>>3 & 1)*32 + (j&31), c = h>>4, within-f4 = h&3,
// half16 = (h>>2) & 1.  512 float4/tile; block bx uses tiles 4bx..4bx+3 =
// 2048 contiguous float4 -> linear coalesced LDS copy; reads are
// conflict-free ds_read_b128 (16-B lane stride). [resubmit r14: broker
// failed on r13 before compile; source functionally identical]

__device__ __forceinline__ float swish(float x) {
    // x * sigmoid(x); v_exp_f32 / v_rcp_f32, abs err ~1e-5 max — far under budget
    float e = __builtin_amdgcn_exp2f(x * -1.442695040888963f);
    return x * __builtin_amdgcn_rcpf(1.0f + e);
}

__global__ void prep_kernel(
    const float* __restrict__ Coords,
    const float* __restrict__ Emb,
    const float* __restrict__ W1,
    const float* __restrict__ b1,
    const float* __restrict__ W2,
    const float* __restrict__ b2,
    float* __restrict__ ws)
{
    const int b = blockIdx.x;
    const int t = threadIdx.x;
    if (b < NN) {
        // A[b][t] = Emb[b] . W1[t][0:F];  B[b][t] = Emb[b] . W1[t][F:2F]
        const float4* w1v = (const float4*)(W1 + t * (2 * FF));
        const float4* ev  = (const float4*)(Emb + b * FF);
        float accA = 0.f, accB = 0.f;
        #pragma unroll
        for (int f4 = 0; f4 < FF / 4; ++f4) {
            const float4 e  = ev[f4];
            const float4 a  = w1v[f4];
            const float4 bq = w1v[FF / 4 + f4];
            accA = fmaf(e.x, a.x,  fmaf(e.y, a.y,  fmaf(e.z, a.z,  fmaf(e.w, a.w,  accA))));
            accB = fmaf(e.x, bq.x, fmaf(e.y, bq.y, fmaf(e.z, bq.z, fmaf(e.w, bq.w, accB))));
        }
        ws[WS_A + b * HID + t] = accA;
        // scatter accB into fragment order (j = b, h = t)
        const int tile = b >> 5;
        const int c    = t >> 4;
        const int hf   = (t >> 3) & 1;
        const int k    = t & 7;
        const int h16  = k >> 2;
        const int lane = hf * 32 + (b & 31);
        const int f4i  = tile * 512 + h16 * 256 + c * 64 + lane;
        ws[WS_B + f4i * 4 + (k & 3)] = accB;
    } else {
        if (t < HID)  ws[WS_B1 + t] = b1[t];
        if (t < OUTF) ws[WS_B2 + t] = b2[t];
        #pragma unroll 1
        for (int n = t; n < NN; n += 64) {
            ws[WS_C4 + n * 4 + 0] = Coords[n * 3 + 0];
            ws[WS_C4 + n * 4 + 1] = Coords[n * 3 + 1];
            ws[WS_C4 + n * 4 + 2] = Coords[n * 3 + 2];
            ws[WS_C4 + n * 4 + 3] = 0.f;
        }
        // W2^T fragments in MFMA B-layout (32x32x16): n = t&31, k = (t>>5)*8 + j
        ushort* w2h = (ushort*)(ws + WS_W2H);
        const int n  = t & 31;
        const int kh = (t >> 5) * 8;
        #pragma unroll
        for (int c = 0; c < 4; ++c) {
            #pragma unroll
            for (int j = 0; j < 8; ++j) {
                const int k = c * 16 + kh + j;
                union { _Float16 h; ushort u; } cv;
                cv.h = (_Float16)W2[n * HID + k];
                w2h[(c * 64 + t) * 8 + j] = cv.u;
            }
        }
    }
}

// DUAL-I ILP with the spill blocker removed: __launch_bounds__(256,2) lifts
// the VGPR cap 128 -> 256. R10/R12 both spilled at cap 128 (FETCH 155-160 MB
// scratch reads vs 5 MB clean single-i in R11); the dual-i register set
// (~140-160 VGPR with tuple-alignment fragmentation) needs the bigger budget.
// Residency drops to ~2-3 blocks/CU, but R11 proved extra TLP doesn't pay;
// per-wave ILP (two independent swish/pack/MFMA chains) is the lever.
// bv stays LDS-resident in fragment order (conflict-free ds_read_b128).
__global__ __launch_bounds__(256, 2) void main_kernel(
    const float* __restrict__ Edges,
    const float* __restrict__ ws,
    float* __restrict__ out)
{
    __shared__ float lds[ITER * HID + HID + ITER * 4 + 8192];
    #define L_A   0
    #define L_B1  (ITER * HID)
    #define L_CI  (ITER * HID + HID)
    #define L_BV  (ITER * HID + HID + ITER * 4)   // 608, f4-aligned

    const int t    = threadIdx.x;
    const int lane = t & 63;
    const int wave = t >> 6;
    const int j0   = blockIdx.x * 128 + wave * 32;
    const int i0   = blockIdx.y * ITER;
    const int p    = lane & 31;
    const int half = lane >> 5;
    const int jp   = j0 + p;

    // ---- stage LDS ----
    {
        const float* srcA = ws + WS_A + (size_t)i0 * HID;   // 512 contiguous floats
        if (t < 128) {
            *(float4*)&lds[L_A + t * 4] = *(const float4*)(srcA + t * 4);
        } else if (t < 144) {
            *(float4*)&lds[L_B1 + (t - 128) * 4] =
                *(const float4*)(ws + WS_B1 + (t - 128) * 4);
        } else if (t < 152) {
            *(float4*)&lds[L_CI + (t - 144) * 4] =
                *(const float4*)(ws + WS_C4 + (size_t)(i0 + (t - 144)) * 4);
        }
        // bv: linear copy of 2048 float4 (block's 4 tiles, fragment order)
        const float4* srcB = (const float4*)(ws + WS_B) + (size_t)blockIdx.x * 2048;
        float4* dstB = (float4*)&lds[L_BV];
        #pragma unroll
        for (int k = 0; k < 8; ++k)
            dstB[t + 256 * k] = srcB[t + 256 * k];
    }

    // ---- loop-invariant state (VGPRs) ----
    const ushort* w2hp = (const ushort*)(ws + WS_W2H);
    halfx8 bh[4];
    #pragma unroll
    for (int c = 0; c < 4; ++c)
        bh[c] = *(const halfx8*)(w2hp + (c * 64 + lane) * 8);

    const float4 cj  = *(const float4*)(ws + WS_C4 + (size_t)jp * 4);
    const float  b2n = ws[WS_B2 + p];

    __syncthreads();

    // Edges software pipeline: two rows in flight
    const float* egp = Edges + (size_t)i0 * NN + jp;
    float eg0 = egp[0];
    float eg1 = egp[NN];

    #pragma unroll 1
    for (int it = 0; it < ITER; it += 2) {
        const float e0 = eg0, e1 = eg1;
        if (it + 2 < ITER) {                 // prefetch next pair
            eg0 = egp[(size_t)(it + 2) * NN];
            eg1 = egp[(size_t)(it + 3) * NN];
        }

        const float4 ci0 = *(const float4*)&lds[L_CI + it * 4];
        const float4 ci1 = *(const float4*)&lds[L_CI + (it + 1) * 4];
        const float dx0 = ci0.x - cj.x, dy0 = ci0.y - cj.y, dz0 = ci0.z - cj.z;
        const float dx1 = ci1.x - cj.x, dy1 = ci1.y - cj.y, dz1 = ci1.z - cj.z;
        const float w0 = e0 * sqrtf(dx0 * dx0 + dy0 * dy0 + dz0 * dz0);
        const float w1 = e1 * sqrtf(dx1 * dx1 + dy1 * dy1 + dz1 * dz1);

        floatx16 acc0, acc1;
        #pragma unroll
        for (int r = 0; r < 16; ++r) { acc0[r] = b2n; acc1[r] = b2n; }
        #pragma unroll
        for (int c = 0; c < 4; ++c) {
            const int ho = c * 16 + half * 8;
            float av0[8], av1[8], b1c[8], bvv[8];
            *(float4*)(av0 + 0) = *(const float4*)&lds[L_A + it * HID + ho];
            *(float4*)(av0 + 4) = *(const float4*)&lds[L_A + it * HID + ho + 4];
            *(float4*)(av1 + 0) = *(const float4*)&lds[L_A + (it + 1) * HID + ho];
            *(float4*)(av1 + 4) = *(const float4*)&lds[L_A + (it + 1) * HID + ho + 4];
            *(float4*)(b1c + 0) = *(const float4*)&lds[L_B1 + ho];
            *(float4*)(b1c + 4) = *(const float4*)&lds[L_B1 + ho + 4];
            // fragment-ordered bv: lo at [wave*512 + c*64 + lane], hi at +256 f4
            *(float4*)(bvv + 0) = *(const float4*)&lds[L_BV + (wave * 512 + c * 64 + lane) * 4];
            *(float4*)(bvv + 4) = *(const float4*)&lds[L_BV + (wave * 512 + 256 + c * 64 + lane) * 4];
            union FragH { fp16x2 h2[4]; halfx8 v; } ah0, ah1;
            #pragma unroll
            for (int jj = 0; jj < 8; jj += 2) {
                const float q0 = fmaf(w0, av0[jj]     + bvv[jj],     b1c[jj]);
                const float q1 = fmaf(w0, av0[jj + 1] + bvv[jj + 1], b1c[jj + 1]);
                const float r0 = fmaf(w1, av1[jj]     + bvv[jj],     b1c[jj]);
                const float r1 = fmaf(w1, av1[jj + 1] + bvv[jj + 1], b1c[jj + 1]);
                ah0.h2[jj >> 1] = __builtin_amdgcn_cvt_pkrtz(swish(q0), swish(q1));
                ah1.h2[jj >> 1] = __builtin_amdgcn_cvt_pkrtz(swish(r0), swish(r1));
            }
            acc0 = __builtin_amdgcn_mfma_f32_32x32x16_f16(ah0.v, bh[c], acc0, 0, 0, 0);
            acc1 = __builtin_amdgcn_mfma_f32_32x32x16_f16(ah1.v, bh[c], acc1, 0, 0, 0);
        }

        // epilogue: C/D layout n = p (output), m = (r&3) + 8*(r>>2) + 4*half (j)
        // each NT dword-store instruction covers two dense 128-B row segments
        float* __restrict__ ob0 = out + ((size_t)(i0 + it)     * NN + j0) * OUTF + p;
        #pragma unroll
        for (int r = 0; r < 16; ++r) {
            const int m = (r & 3) + 8 * (r >> 2) + 4 * half;
            __builtin_nontemporal_store(swish(acc0[r]), ob0 + m * OUTF);
        }
        float* __restrict__ ob1 = out + ((size_t)(i0 + it + 1) * NN + j0) * OUTF + p;
        #pragma unroll
        for (int r = 0; r < 16; ++r) {
            const int m = (r & 3) + 8 * (r >> 2) + 4 * half;
            __builtin_nontemporal_store(swish(acc1[r]), ob1 + m * OUTF);
        }
    }
}

extern "C" void kernel_launch(void* const* d_in, const int* in_sizes, int n_in,
                              void* d_out, int out_size, void* d_ws, size_t ws_size,
                              hipStream_t stream)
{
    const float* Edges  = (const float*)d_in[0];
    const float* Coords = (const float*)d_in[1];
    const float* Emb    = (const float*)d_in[2];
    const float* W1     = (const float*)d_in[3];
    const float* b1     = (const float*)d_in[4];
    const float* W2     = (const float*)d_in[5];
    const float* b2     = (const float*)d_in[6];
    float* ws  = (float*)d_ws;
    float* out = (float*)d_out;

    hipLaunchKernelGGL(prep_kernel, dim3(NN + 1), dim3(64), 0, stream,
                       Coords, Emb, W1, b1, W2, b2, ws);
    hipLaunchKernelGGL(main_kernel, dim3(NN / 128, NN / ITER), dim3(256), 0, stream,
                       Edges, ws, out);
}